// Round 1
// baseline (3005.350 us; speedup 1.0000x reference)
//
#include <hip/hip_runtime.h>
#include <math.h>

#define DEPTH 18
#define HS 128

__device__ __forceinline__ float sigf(float x) { return 1.0f / (1.0f + expf(-x)); }

// Build B' [384][640] in ws:
// rows 0-127   (emb): [W_iou | W_f | W_f]
// rows 128-255 (hl) : [U_iou | U_f |  0 ]
// rows 256-383 (hr) : [U_iou |  0  | U_f]
__global__ __launch_bounds__(256) void prep_kernel(
    const float* __restrict__ W_iou, const float* __restrict__ W_f,
    const float* __restrict__ U_iou, const float* __restrict__ U_f,
    float* __restrict__ Bp)
{
    int idx = blockIdx.x * 256 + threadIdx.x;
    if (idx >= 384 * 640) return;
    int r = idx / 640, cc = idx % 640;
    float v;
    if (r < 128) {
        v = (cc < 384) ? W_iou[r * 384 + cc] : W_f[r * 128 + ((cc - 384) & 127)];
    } else if (r < 256) {
        int k = r - 128;
        v = (cc < 384) ? U_iou[k * 384 + cc] : ((cc < 512) ? U_f[k * 128 + (cc - 384)] : 0.0f);
    } else {
        int k = r - 256;
        v = (cc < 384) ? U_iou[k * 384 + cc] : ((cc < 512) ? 0.0f : U_f[k * 128 + (cc - 512)]);
    }
    Bp[idx] = v;
}

// Leaf level: C[16x384] = A[16x128] @ W_iou[128x384], then cell with c_agg=0.
__global__ __launch_bounds__(256) void leaf_kernel(
    const int* __restrict__ x, const int* __restrict__ mask,
    const float* __restrict__ E, const float* __restrict__ W_iou,
    const float* __restrict__ b_iou_x, const float* __restrict__ b_iou_h,
    float* __restrict__ h, float* __restrict__ c, int s0, int M)
{
    __shared__ float A[16][128];
    __shared__ float Bs[16][384];
    int t = threadIdx.x;
    int n0 = s0 + blockIdx.x * 16;
    int lastn = s0 + M;
    const float4* E4 = (const float4*)E;

    for (int idx = t; idx < 16 * 32; idx += 256) {
        int ni = idx >> 5, f4 = idx & 31;
        int n = n0 + ni; if (n >= lastn) n = s0;
        int mk = mask[n];
        float m = (float)mk;
        float4 v = E4[(size_t)(x[n] * mk) * 32 + f4];
        v.x *= m; v.y *= m; v.z *= m; v.w *= m;
        *(float4*)&A[ni][f4 * 4] = v;
    }

    float acc[4][6];
#pragma unroll
    for (int s = 0; s < 4; s++)
#pragma unroll
        for (int r = 0; r < 6; r++) acc[s][r] = 0.0f;

    int c_low = t & 63, nslot = t >> 6;
    const float4* B4 = (const float4*)W_iou;

    for (int kc = 0; kc < 128; kc += 16) {
        __syncthreads();
        for (int idx = t; idx < 16 * 96; idx += 256) {
            int rr = idx / 96, c4 = idx % 96;
            *(float4*)&Bs[rr][c4 * 4] = B4[(size_t)(kc + rr) * 96 + c4];
        }
        __syncthreads();
#pragma unroll
        for (int k4 = 0; k4 < 4; k4++) {
            float4 av[4];
#pragma unroll
            for (int s = 0; s < 4; s++) av[s] = *(const float4*)&A[nslot + 4 * s][kc + k4 * 4];
#pragma unroll
            for (int kk = 0; kk < 4; kk++) {
                float bv[6];
#pragma unroll
                for (int r = 0; r < 6; r++) bv[r] = Bs[k4 * 4 + kk][c_low + 64 * r];
#pragma unroll
                for (int s = 0; s < 4; s++) {
                    float a = kk == 0 ? av[s].x : kk == 1 ? av[s].y : kk == 2 ? av[s].z : av[s].w;
#pragma unroll
                    for (int r = 0; r < 6; r++) acc[s][r] = fmaf(a, bv[r], acc[s][r]);
                }
            }
        }
    }

#pragma unroll
    for (int s = 0; s < 4; s++) {
        int n = n0 + nslot + 4 * s;
        if (n >= lastn) continue;
        float m = (float)mask[n];
#pragma unroll
        for (int j2 = 0; j2 < 2; j2++) {
            int j = c_low + 64 * j2;
            float iv = acc[s][0 + j2] + m * b_iou_x[j]       + b_iou_h[j];
            float ov = acc[s][2 + j2] + m * b_iou_x[j + 128] + b_iou_h[j + 128];
            float uv = acc[s][4 + j2] + m * b_iou_x[j + 256] + b_iou_h[j + 256];
            float cn = sigf(iv) * tanhf(uv);
            float hn = sigf(ov) * tanhf(cn);
            c[(size_t)n * HS + j] = cn;
            h[(size_t)n * HS + j] = hn;
        }
    }
}

// Internal level: C[16x640] = A[16x384] @ B'[384x640], A = [m*emb | hl | hr].
__global__ __launch_bounds__(256) void lvl_kernel(
    const int* __restrict__ x, const int* __restrict__ mask,
    const float* __restrict__ E, const float* __restrict__ Bp,
    const float* __restrict__ b_iou_x, const float* __restrict__ b_f_x,
    const float* __restrict__ b_iou_h, const float* __restrict__ b_f_h,
    float* __restrict__ h, float* __restrict__ c, int s0, int M)
{
    __shared__ float A[16][384];
    __shared__ float Bs[12][640];
    int t = threadIdx.x;
    int n0 = s0 + blockIdx.x * 16;
    int lastn = s0 + M;
    const float4* E4 = (const float4*)E;
    const float4* h4 = (const float4*)h;

    for (int idx = t; idx < 16 * 96; idx += 256) {
        int ni = idx / 96; int rem = idx % 96; int part = rem >> 5; int f4 = rem & 31;
        int n = n0 + ni; if (n >= lastn) n = s0;
        float4 v;
        if (part == 0) {
            int mk = mask[n];
            float m = (float)mk;
            v = E4[(size_t)(x[n] * mk) * 32 + f4];
            v.x *= m; v.y *= m; v.z *= m; v.w *= m;
        } else {
            v = h4[(size_t)(2 * n + part) * 32 + f4];
        }
        *(float4*)&A[ni][rem * 4] = v;
    }

    float acc[4][10];
#pragma unroll
    for (int s = 0; s < 4; s++)
#pragma unroll
        for (int r = 0; r < 10; r++) acc[s][r] = 0.0f;

    int c_low = t & 63, nslot = t >> 6;
    const float4* B4 = (const float4*)Bp;

    for (int kc = 0; kc < 384; kc += 12) {
        __syncthreads();
        for (int idx = t; idx < 12 * 160; idx += 256) {
            int rr = idx / 160, c4 = idx % 160;
            *(float4*)&Bs[rr][c4 * 4] = B4[(size_t)(kc + rr) * 160 + c4];
        }
        __syncthreads();
#pragma unroll
        for (int k4 = 0; k4 < 3; k4++) {
            float4 av[4];
#pragma unroll
            for (int s = 0; s < 4; s++) av[s] = *(const float4*)&A[nslot + 4 * s][kc + k4 * 4];
#pragma unroll
            for (int kk = 0; kk < 4; kk++) {
                float bv[10];
#pragma unroll
                for (int r = 0; r < 10; r++) bv[r] = Bs[k4 * 4 + kk][c_low + 64 * r];
#pragma unroll
                for (int s = 0; s < 4; s++) {
                    float a = kk == 0 ? av[s].x : kk == 1 ? av[s].y : kk == 2 ? av[s].z : av[s].w;
#pragma unroll
                    for (int r = 0; r < 10; r++) acc[s][r] = fmaf(a, bv[r], acc[s][r]);
                }
            }
        }
    }

#pragma unroll
    for (int s = 0; s < 4; s++) {
        int n = n0 + nslot + 4 * s;
        if (n >= lastn) continue;
        float m = (float)mask[n];
#pragma unroll
        for (int j2 = 0; j2 < 2; j2++) {
            int j = c_low + 64 * j2;
            float iv  = acc[s][0 + j2] + m * b_iou_x[j]       + b_iou_h[j];
            float ov  = acc[s][2 + j2] + m * b_iou_x[j + 128] + b_iou_h[j + 128];
            float uv  = acc[s][4 + j2] + m * b_iou_x[j + 256] + b_iou_h[j + 256];
            float flp = acc[s][6 + j2] + m * b_f_x[j] + b_f_h[j];
            float frp = acc[s][8 + j2] + m * b_f_x[j] + b_f_h[j];
            float cl = c[(size_t)(2 * n + 1) * HS + j];
            float cr = c[(size_t)(2 * n + 2) * HS + j];
            float cn = sigf(iv) * tanhf(uv) + sigf(flp) * cl + sigf(frp) * cr;
            float hn = sigf(ov) * tanhf(cn);
            c[(size_t)n * HS + j] = cn;
            h[(size_t)n * HS + j] = hn;
        }
    }
}

extern "C" void kernel_launch(void* const* d_in, const int* in_sizes, int n_in,
                              void* d_out, int out_size, void* d_ws, size_t ws_size,
                              hipStream_t stream)
{
    const int*   x       = (const int*)d_in[0];
    const int*   mask    = (const int*)d_in[1];
    const float* E       = (const float*)d_in[2];
    const float* W_iou   = (const float*)d_in[3];
    const float* b_iou_x = (const float*)d_in[4];
    const float* W_f     = (const float*)d_in[5];
    const float* b_f_x   = (const float*)d_in[6];
    const float* U_iou   = (const float*)d_in[7];
    const float* b_iou_h = (const float*)d_in[8];
    const float* U_f     = (const float*)d_in[9];
    const float* b_f_h   = (const float*)d_in[10];

    float* h  = (float*)d_out;
    float* Bp = (float*)d_ws;                          // 384*640*4 = 983 KB
    float* c  = (float*)((char*)d_ws + (1 << 20));     // N*128*4 = 134 MB

    prep_kernel<<<960, 256, 0, stream>>>(W_iou, W_f, U_iou, U_f, Bp);

    {   // leaves, lvl = 17
        int s0 = (1 << 17) - 1, M = 1 << 17;
        leaf_kernel<<<M / 16, 256, 0, stream>>>(x, mask, E, W_iou, b_iou_x, b_iou_h, h, c, s0, M);
    }
    for (int lvl = 16; lvl >= 0; --lvl) {
        int s0 = (1 << lvl) - 1, M = 1 << lvl;
        int blocks = (M + 15) / 16;
        lvl_kernel<<<blocks, 256, 0, stream>>>(x, mask, E, Bp, b_iou_x, b_f_x, b_iou_h, b_f_h, h, c, s0, M);
    }
}

// Round 2
// 845.141 us; speedup vs baseline: 3.5560x; 3.5560x over previous
//
#include <hip/hip_runtime.h>
#include <math.h>

typedef unsigned short u16;
typedef unsigned int u32;
typedef float f32x4 __attribute__((ext_vector_type(4)));
typedef short bfrag __attribute__((ext_vector_type(8)));
typedef u16 u16x8 __attribute__((ext_vector_type(8)));

#define HS 128

__device__ __forceinline__ float sigf(float x) { return 1.0f / (1.0f + __expf(-x)); }
__device__ __forceinline__ u16 f2bf(float f) {
    u32 u = __float_as_uint(f);
    return (u16)((u + 0x7FFFu + ((u >> 16) & 1u)) >> 16);
}
__device__ __forceinline__ float bf2f(u16 h) { return __uint_as_float(((u32)h) << 16); }

// ---------------- prep: build pre-swizzled bf16 hi/lo B tiles in ws ----------------
// Internal B' [384 x 640]: rows 0-127 emb:[W_iou|W_f|W_f], 128-255 hl:[U_iou|U_f|0],
// 256-383 hr:[U_iou|0|U_f].  Leaf B [128 x 384] = W_iou.
// ws image per K-chunk kc (32 k): for each col: 8 chunks of 8 bf16 (16B);
// chunk id c0 = half*4 + g (k = g*8+j), stored at c0 ^ (col&7).
__device__ __forceinline__ float bval_int(int k, int col,
    const float* W_iou, const float* W_f, const float* U_iou, const float* U_f)
{
    if (col < 384) {
        if (k < 128) return W_iou[k * 384 + col];
        if (k < 256) return U_iou[(k - 128) * 384 + col];
        return U_iou[(k - 256) * 384 + col];
    } else if (col < 512) {
        int cc = col - 384;
        if (k < 128) return W_f[k * 128 + cc];
        if (k < 256) return U_f[(k - 128) * 128 + cc];
        return 0.0f;
    } else {
        int cc = col - 512;
        if (k < 128) return W_f[k * 128 + cc];
        if (k < 256) return 0.0f;
        return U_f[(k - 256) * 128 + cc];
    }
}

__global__ __launch_bounds__(256) void prep_kernel(
    const float* __restrict__ W_iou, const float* __restrict__ W_f,
    const float* __restrict__ U_iou, const float* __restrict__ U_f,
    u16* __restrict__ Bint, u16* __restrict__ Bleaf)
{
    int idx = blockIdx.x * 256 + threadIdx.x;
    if (idx < 245760) {  // internal: 12 chunks * 640 cols * 4 g * 8 j
        int j = idx & 7, g = (idx >> 3) & 3;
        int r5 = idx >> 5;
        int col = r5 % 640, kc = r5 / 640;
        int k = kc * 32 + g * 8 + j;
        float v = bval_int(k, col, W_iou, W_f, U_iou, U_f);
        u16 vh = f2bf(v);
        u16 vl = f2bf(v - bf2f(vh));
        size_t base = (size_t)(kc * 640 + col) * 64;
        Bint[base + (size_t)((g) ^ (col & 7)) * 8 + j] = vh;
        Bint[base + (size_t)((4 | g) ^ (col & 7)) * 8 + j] = vl;
    } else {
        int i2 = idx - 245760;  // leaf: 4 chunks * 384 cols * 4 g * 8 j
        if (i2 >= 49152) return;
        int j = i2 & 7, g = (i2 >> 3) & 3;
        int r5 = i2 >> 5;
        int col = r5 % 384, kc = r5 / 384;
        int k = kc * 32 + g * 8 + j;
        float v = W_iou[k * 384 + col];
        u16 vh = f2bf(v);
        u16 vl = f2bf(v - bf2f(vh));
        size_t base = (size_t)(kc * 384 + col) * 64;
        Bleaf[base + (size_t)((g) ^ (col & 7)) * 8 + j] = vh;
        Bleaf[base + (size_t)((4 | g) ^ (col & 7)) * 8 + j] = vl;
    }
}

// ---------------- fused level GEMM + LSTM cell ----------------
// Block: 512 threads = 8 waves (2 row x 4 col). BM=64 rows, BK=32.
// Wave tile: 32 rows x (NCF*16) cols; acc = 2 x NCF f32x4 frags.
// Split-3: AhBh + AlBh + AhBl via mfma_f32_16x16x32_bf16.
template<int NCOL, int NKC, int NCF, bool INTERNAL>
__global__ __launch_bounds__(512) void gemm_lvl(
    const int* __restrict__ x, const int* __restrict__ mask,
    const float* __restrict__ E, const u16* __restrict__ Bg,
    const float* __restrict__ b_iou_x, const float* __restrict__ b_f_x,
    const float* __restrict__ b_iou_h, const float* __restrict__ b_f_h,
    float* __restrict__ h, float* __restrict__ c, int s0, int M)
{
    __shared__ __align__(16) u16 ldsA[64 * 64];
    __shared__ __align__(16) u16 ldsB[NCOL * 64];
    const int t = threadIdx.x;
    const int n0 = s0 + blockIdx.x * 64;
    const int lastn = s0 + M;
    const int l = t & 63, wid = t >> 6;
    const int wr = wid >> 2, wc = wid & 3;
    const int lr = l & 15, lg = l >> 4, sw = lr & 7;

    f32x4 acc0[NCF], acc1[NCF];
    const f32x4 zz = {0.0f, 0.0f, 0.0f, 0.0f};
#pragma unroll
    for (int i = 0; i < NCF; i++) { acc0[i] = zz; acc1[i] = zz; }

    const int aoff0h = (32 * wr + lr) * 64 + ((lg ^ sw)) * 8;
    const int aoff0l = (32 * wr + lr) * 64 + (((4 | lg) ^ sw)) * 8;
    const int boffh  = (NCF * 16 * wc + lr) * 64 + ((lg ^ sw)) * 8;
    const int boffl  = (NCF * 16 * wc + lr) * 64 + (((4 | lg) ^ sw)) * 8;

    const int srow = t >> 2, sg = t & 3;

    for (int kc = 0; kc < NKC; ++kc) {
        __syncthreads();
        // stage B: linear global_load_lds (source pre-swizzled)
        const u16* bsrc = Bg + (size_t)kc * (NCOL * 64);
#pragma unroll
        for (int s = 0; s < NCOL / 64; ++s) {
            int off = (s * 512 + t) * 8;
            __builtin_amdgcn_global_load_lds(
                (const __attribute__((address_space(1))) void*)(bsrc + off),
                (__attribute__((address_space(3))) void*)(ldsB + off), 16, 0, 0);
        }
        // stage A: gather fp32 slice, split hi/lo, swizzled ds_write
        if (t < 256) {
            int n = n0 + srow; if (n >= lastn) n = s0;
            int kk = kc * 32 + sg * 8;
            const float* src; float scale = 1.0f;
            if (!INTERNAL || kk < 128) {
                int mk = mask[n]; scale = (float)mk;
                src = E + (size_t)(x[n] * mk) * HS + kk;
            } else if (kk < 256) {
                src = h + (size_t)(2 * n + 1) * HS + (kk - 128);
            } else {
                src = h + (size_t)(2 * n + 2) * HS + (kk - 256);
            }
            float4 v0 = *(const float4*)src;
            float4 v1 = *(const float4*)(src + 4);
            float vs[8] = {v0.x * scale, v0.y * scale, v0.z * scale, v0.w * scale,
                           v1.x * scale, v1.y * scale, v1.z * scale, v1.w * scale};
            u16x8 Hh, Ll;
#pragma unroll
            for (int i = 0; i < 8; i++) {
                u16 hh = f2bf(vs[i]); Hh[i] = hh; Ll[i] = f2bf(vs[i] - bf2f(hh));
            }
            int rs = srow & 7;
            *(u16x8*)&ldsA[srow * 64 + ((sg ^ rs)) * 8] = Hh;
            *(u16x8*)&ldsA[srow * 64 + (((4 | sg) ^ rs)) * 8] = Ll;
        }
        __syncthreads();

        bfrag a0h = *(const bfrag*)&ldsA[aoff0h];
        bfrag a0l = *(const bfrag*)&ldsA[aoff0l];
        bfrag a1h = *(const bfrag*)&ldsA[aoff0h + 16 * 64];
        bfrag a1l = *(const bfrag*)&ldsA[aoff0l + 16 * 64];
#pragma unroll
        for (int cf = 0; cf < NCF; ++cf) {
            bfrag bh = *(const bfrag*)&ldsB[boffh + cf * 1024];
            bfrag bl = *(const bfrag*)&ldsB[boffl + cf * 1024];
            acc0[cf] = __builtin_amdgcn_mfma_f32_16x16x32_bf16(a0h, bh, acc0[cf], 0, 0, 0);
            acc1[cf] = __builtin_amdgcn_mfma_f32_16x16x32_bf16(a1h, bh, acc1[cf], 0, 0, 0);
            acc0[cf] = __builtin_amdgcn_mfma_f32_16x16x32_bf16(a0l, bh, acc0[cf], 0, 0, 0);
            acc1[cf] = __builtin_amdgcn_mfma_f32_16x16x32_bf16(a1l, bh, acc1[cf], 0, 0, 0);
            acc0[cf] = __builtin_amdgcn_mfma_f32_16x16x32_bf16(a0h, bl, acc0[cf], 0, 0, 0);
            acc1[cf] = __builtin_amdgcn_mfma_f32_16x16x32_bf16(a1h, bl, acc1[cf], 0, 0, 0);
        }
    }

    // epilogue: 4 slabs of 16 rows via LDS C-slab (reuses ldsB)
    float* Cs = (float*)ldsB;
#pragma unroll 1
    for (int s = 0; s < 4; ++s) {
        __syncthreads();
        if (wr == (s >> 1)) {
            if ((s & 1) == 0) {
#pragma unroll
                for (int cf = 0; cf < NCF; cf++)
#pragma unroll
                    for (int r = 0; r < 4; r++)
                        Cs[(lg * 4 + r) * NCOL + NCF * 16 * wc + 16 * cf + lr] = acc0[cf][r];
            } else {
#pragma unroll
                for (int cf = 0; cf < NCF; cf++)
#pragma unroll
                    for (int r = 0; r < 4; r++)
                        Cs[(lg * 4 + r) * NCOL + NCF * 16 * wc + 16 * cf + lr] = acc1[cf][r];
            }
        }
        __syncthreads();
        for (int idx = t; idx < 16 * HS; idx += 512) {
            int rsl = idx >> 7, j = idx & 127;
            int n = n0 + 16 * s + rsl;
            if (n < lastn) {
                float m = (float)mask[n];
                float iv = Cs[rsl * NCOL + j]          + m * b_iou_x[j]          + b_iou_h[j];
                float ov = Cs[rsl * NCOL + HS + j]     + m * b_iou_x[HS + j]     + b_iou_h[HS + j];
                float uv = Cs[rsl * NCOL + 2 * HS + j] + m * b_iou_x[2 * HS + j] + b_iou_h[2 * HS + j];
                float cn;
                if (INTERNAL) {
                    float fl = Cs[rsl * NCOL + 3 * HS + j] + m * b_f_x[j] + b_f_h[j];
                    float fr = Cs[rsl * NCOL + 4 * HS + j] + m * b_f_x[j] + b_f_h[j];
                    float clv = c[(size_t)(2 * n + 1) * HS + j];
                    float crv = c[(size_t)(2 * n + 2) * HS + j];
                    cn = sigf(iv) * tanhf(uv) + sigf(fl) * clv + sigf(fr) * crv;
                } else {
                    cn = sigf(iv) * tanhf(uv);
                }
                float hn = sigf(ov) * tanhf(cn);
                c[(size_t)n * HS + j] = cn;
                h[(size_t)n * HS + j] = hn;
            }
        }
    }
}

extern "C" void kernel_launch(void* const* d_in, const int* in_sizes, int n_in,
                              void* d_out, int out_size, void* d_ws, size_t ws_size,
                              hipStream_t stream)
{
    const int*   x       = (const int*)d_in[0];
    const int*   mask    = (const int*)d_in[1];
    const float* E       = (const float*)d_in[2];
    const float* W_iou   = (const float*)d_in[3];
    const float* b_iou_x = (const float*)d_in[4];
    const float* W_f     = (const float*)d_in[5];
    const float* b_f_x   = (const float*)d_in[6];
    const float* U_iou   = (const float*)d_in[7];
    const float* b_iou_h = (const float*)d_in[8];
    const float* U_f     = (const float*)d_in[9];
    const float* b_f_h   = (const float*)d_in[10];

    float* h   = (float*)d_out;
    u16* Bint  = (u16*)d_ws;                              // 983040 B
    u16* Bleaf = (u16*)((char*)d_ws + 983040);            // 196608 B
    float* c   = (float*)((char*)d_ws + 1179648);         // N*128*4 B

    prep_kernel<<<1152, 256, 0, stream>>>(W_iou, W_f, U_iou, U_f, Bint, Bleaf);

    {   // leaves, lvl = 17: K=128, 384 cols
        int s0 = (1 << 17) - 1, M = 1 << 17;
        gemm_lvl<384, 4, 6, false><<<M / 64, 512, 0, stream>>>(
            x, mask, E, Bleaf, b_iou_x, b_f_x, b_iou_h, b_f_h, h, c, s0, M);
    }
    for (int lvl = 16; lvl >= 0; --lvl) {
        int s0 = (1 << lvl) - 1, M = 1 << lvl;
        int blocks = (M + 63) / 64;
        gemm_lvl<640, 12, 10, true><<<blocks, 512, 0, stream>>>(
            x, mask, E, Bint, b_iou_x, b_f_x, b_iou_h, b_f_h, h, c, s0, M);
    }
}